// Round 5
// baseline (223.450 us; speedup 1.0000x reference)
//
#include <hip/hip_runtime.h>
#include <hip/hip_bf16.h>
#include <stdint.h>

// RhymeLoss: mean over b in [0,4096), pairs i<j in [0,32) of
//   same(i,j) ? 1 - cos(u_i,u_j) : relu(cos(u_i,u_j) - 0.5)
//
// R5 structure: block = 256 threads (4 waves) handles 4 batches.
//  Phase 1 (staging, copy-kernel pattern): the block streams its 128 KiB
//   input window with fully-coalesced float4 loads (each wave instruction
//   = contiguous 1 KiB, the m13/fill pattern that hits 6-7 TB/s), converts
//   fp32->bf16 in-register, ds_write_b64 into a per-batch staged layout.
//   bf16 staging halves LDS (69 KiB/block) -> 2 blocks/CU, 8 waves/CU.
//   R1-R4 post-mortem: every <=16-wave structure with vmcnt(0)-per-small-
//   batch plateaued at 1.7 TB/s while the harness's own 512 MiB fill ran
//   at 7 TB/s in the same graph -> mimic the fill's access shape.
//  Phase 2: wave w computes batch w's gram from LDS. ds_read_b128 yields a
//   whole bf16x8 MFMA fragment (A-frag == B-frag for a gram); 3 tiles
//   (00,01,11), norms from the gram diagonal, loss epilogue, one
//   atomicAdd per wave.
// LDS row stride 264 shorts (+16B pad): b128 start bank = 4*(c+q) mod 32,
// uniform 8 touches/bank (the b128 minimum) -> conflict-free.

typedef short bf16x8 __attribute__((ext_vector_type(8)));   // 8 bf16 (4 VGPRs)
typedef short bf16x4 __attribute__((ext_vector_type(4)));   // 4 bf16 (2 VGPRs)
typedef float f32x4  __attribute__((ext_vector_type(4)));

#define MARGIN 0.5f
#define EPS_NORM 1e-8f
#define NPAIR_INV (1.0f / 2031616.0f)   // 1 / (4096 * 496)
#define ROW_S   264                      // shorts per staged row (256 + 8 pad)
#define BATCH_S (32 * ROW_S)             // shorts per staged batch (8448)

// fp32 -> bf16 round-to-nearest-even (inputs are finite, no NaN handling)
static __device__ __forceinline__ short f2bf(float f) {
    unsigned u = __float_as_uint(f);
    u += 0x7fffu + ((u >> 16) & 1u);
    return (short)(u >> 16);
}

__global__ __launch_bounds__(256) void rhyme_loss_kernel(
    const float* __restrict__ emb,   // [4096][32][256] fp32
    const int*   __restrict__ sch,   // [4096][32] int32
    float*       __restrict__ out)   // [1] fp32 (pre-zeroed)
{
    __shared__ short s_stage[4 * BATCH_S];   // 67,584 B
    __shared__ float s_diag[4][32];
    __shared__ float s_inv[4][32];
    __shared__ int   s_sch[4][32];

    const int t    = threadIdx.x;
    const int wv   = t >> 6;             // wave 0..3 (= batch owner in phase 2)
    const int lane = t & 63;

    // ---- Phase 1: coalesced stream of 4 batches -> bf16 in LDS ----
    // Flat float index f = (i*256 + t)*4: batch g = (4i+wv)>>5,
    // row r = (4i+wv)&31, col k = 4*lane. Each wave instruction reads a
    // contiguous 1 KiB run; every (g,r) row is written exactly once.
    const float* gbase = emb + (size_t)blockIdx.x * 32768 + 4 * t;

    if (t < 128)   // scheme for 4 batches, coalesced dwords
        s_sch[t >> 5][t & 31] = sch[(size_t)blockIdx.x * 128 + t];

    #pragma unroll
    for (int i0 = 0; i0 < 32; i0 += 8) {
        float4 v[8];
        #pragma unroll
        for (int j = 0; j < 8; ++j)
            v[j] = *(const float4*)(gbase + (size_t)(i0 + j) * 1024);
        #pragma unroll
        for (int j = 0; j < 8; ++j) {
            const int row128 = 4 * (i0 + j) + wv;    // 0..127
            const int g = row128 >> 5, r = row128 & 31;
            bf16x4 h;
            h[0] = f2bf(v[j].x); h[1] = f2bf(v[j].y);
            h[2] = f2bf(v[j].z); h[3] = f2bf(v[j].w);
            *(bf16x4*)(&s_stage[g * BATCH_S + r * ROW_S + 4 * lane]) = h;
        }
    }
    __syncthreads();

    // ---- Phase 2: wave wv computes gram of batch wv from LDS ----
    const int q = lane >> 4;             // quad 0..3 -> k-offset q*8
    const int c = lane & 15;             // fragment row (= C col)

    const short* r0 = s_stage + wv * BATCH_S + c * ROW_S + 8 * q;         // row c
    const short* r1 = s_stage + wv * BATCH_S + (16 + c) * ROW_S + 8 * q;  // row 16+c

    f32x4 acc00 = {0.f, 0.f, 0.f, 0.f};   // rows 0-15  x cols 0-15
    f32x4 acc01 = {0.f, 0.f, 0.f, 0.f};   // rows 0-15  x cols 16-31
    f32x4 acc11 = {0.f, 0.f, 0.f, 0.f};   // rows 16-31 x cols 16-31
    // (tile 10 is the i>j mirror of 01 -> never needed)

    #pragma unroll
    for (int kc = 0; kc < 256; kc += 32) {
        bf16x8 f0 = *(const bf16x8*)(r0 + kc);   // one ds_read_b128 = full frag
        bf16x8 f1 = *(const bf16x8*)(r1 + kc);
        // A-frag and B-frag of a gram share the same per-lane data.
        acc00 = __builtin_amdgcn_mfma_f32_16x16x32_bf16(f0, f0, acc00, 0, 0, 0);
        acc01 = __builtin_amdgcn_mfma_f32_16x16x32_bf16(f0, f1, acc01, 0, 0, 0);
        acc11 = __builtin_amdgcn_mfma_f32_16x16x32_bf16(f1, f1, acc11, 0, 0, 0);
    }

    // C/D layout (m89-verified): col = lane&15, row = (lane>>4)*4 + reg.
    // Diagonal of tiles 00/11: row==col -> reg = c - 4*q when in [0,4).
    const int dreg = c - 4 * q;
    if (dreg >= 0 && dreg < 4) {
        s_diag[wv][c]      = acc00[dreg];   // ||u_c||^2
        s_diag[wv][16 + c] = acc11[dreg];   // ||u_{16+c}||^2
    }
    __syncthreads();

    if (lane < 32) {
        float d = s_diag[wv][lane];
        s_inv[wv][lane] = 1.0f / fmaxf(sqrtf(d), EPS_NORM);
    }
    __syncthreads();

    const float invj0 = s_inv[wv][c];
    const float invj1 = s_inv[wv][16 + c];
    const int   sj0   = s_sch[wv][c];
    const int   sj1   = s_sch[wv][16 + c];

    float sum = 0.0f;
    #pragma unroll
    for (int r = 0; r < 4; ++r) {
        const int   i0    = q * 4 + r;
        const float inv_i = s_inv[wv][i0];
        const int   si    = s_sch[wv][i0];

        // tile 01: i = i0 (<16), j = 16+c  -> always i<j
        {
            float sim = acc01[r] * inv_i * invj1;
            sum += (si == sj1) ? (1.0f - sim) : fmaxf(sim - MARGIN, 0.0f);
        }
        if (i0 < c) {
            // tile 00: i = i0, j = c
            float sim = acc00[r] * inv_i * invj0;
            sum += (si == sj0) ? (1.0f - sim) : fmaxf(sim - MARGIN, 0.0f);
            // tile 11: i = 16+i0, j = 16+c
            float sim2 = acc11[r] * s_inv[wv][16 + i0] * invj1;
            sum += (s_sch[wv][16 + i0] == sj1) ? (1.0f - sim2)
                                               : fmaxf(sim2 - MARGIN, 0.0f);
        }
    }

    // wave-64 reduction
    #pragma unroll
    for (int off = 32; off > 0; off >>= 1)
        sum += __shfl_down(sum, off, 64);

    if (lane == 0)
        atomicAdd(out, sum * NPAIR_INV);
}

extern "C" void kernel_launch(void* const* d_in, const int* in_sizes, int n_in,
                              void* d_out, int out_size, void* d_ws, size_t ws_size,
                              hipStream_t stream) {
    const float* emb = (const float*)d_in[0];
    const int*   sch = (const int*)d_in[1];
    float*       out = (float*)d_out;

    hipMemsetAsync(out, 0, sizeof(float), stream);   // d_out is poisoned 0xAA
    rhyme_loss_kernel<<<dim3(1024), dim3(256), 0, stream>>>(emb, sch, out);
}

// Round 6
// 215.384 us; speedup vs baseline: 1.0375x; 1.0375x over previous
//
#include <hip/hip_runtime.h>
#include <hip/hip_bf16.h>
#include <stdint.h>

// RhymeLoss: mean over b in [0,4096), pairs i<j in [0,32) of
//   same(i,j) ? 1 - cos(u_i,u_j) : relu(cos(u_i,u_j) - 0.5)
//
// R6 thesis: TLP, not per-wave ILP. R1-R5 post-mortem: every structure
// (interleaved VGPR loads, sched_barrier preload, LDS-DMA, copy-style
// staging) plateaued at ~1.5-1.7 TB/s with 4-11 waves/CU, while the
// harness's own fill and the m13 copy hit 6-7 TB/s with ~32 waves/CU of
// dead-simple loops. Per-wave in-flight is compiler-capped at ~1-2 loads
// (proved by R2/R3: VGPR stayed 48); the only remaining lever is wave count.
//
// Structure: K-SPLIT. Each batch's K=256 gram reduction is split over two
// waves (K=128 each) -> 8192 waves = 32 waves/CU (HW max). Block = 4 waves
// = 2 batches. Partial accumulators (exact: MFMA sum over K commutes)
// combine via a 12 KB LDS exchange; norms from the combined gram diagonal;
// loss epilogue on the kh==0 wave of each pair; one atomicAdd per batch.
// No staging LDS -> occupancy limited only by VGPR; __launch_bounds__(256,8)
// forces VGPR<=64 so all 8 waves/SIMD are resident.

typedef short bf16x8 __attribute__((ext_vector_type(8)));   // 8 bf16 (4 VGPRs)
typedef float f32x4  __attribute__((ext_vector_type(4)));

#define MARGIN 0.5f
#define EPS_NORM 1e-8f
#define NPAIR_INV (1.0f / 2031616.0f)   // 1 / (4096 * 496)

// fp32 -> bf16 round-to-nearest-even (inputs are finite, no NaN handling)
static __device__ __forceinline__ short f2bf(float f) {
    unsigned u = __float_as_uint(f);
    u += 0x7fffu + ((u >> 16) & 1u);
    return (short)(u >> 16);
}

__global__ __launch_bounds__(256, 8) void rhyme_loss_kernel(
    const float* __restrict__ emb,   // [4096][32][256] fp32
    const int*   __restrict__ sch,   // [4096][32] int32
    float*       __restrict__ out)   // [1] fp32 (pre-zeroed)
{
    __shared__ f32x4 s_acc[4][3][64];   // 12,288 B: per-wave partial accs
    __shared__ float s_diag[2][32];
    __shared__ float s_inv[2][32];
    __shared__ int   s_sch[2][32];

    const int t    = threadIdx.x;
    const int wv   = t >> 6;            // wave 0..3
    const int lane = t & 63;
    const int g    = wv >> 1;           // batch slot within block (0,1)
    const int kh   = wv & 1;            // K-half (0: k<128, 1: k>=128)
    const int b    = blockIdx.x * 2 + g;

    const int q = lane >> 4;            // quad 0..3 -> k-offset q*8
    const int c = lane & 15;            // fragment row (= C col)

    if (t < 64)   // scheme for both batches, coalesced
        s_sch[t >> 5][t & 31] = sch[(size_t)blockIdx.x * 64 + t];

    // Lane's global source rows: c and 16+c, this wave's K-half.
    const float* base0 = emb + (size_t)b * 8192 + (size_t)c * 256 + kh * 128 + q * 8;
    const float* base1 = base0 + 16 * 256;

    f32x4 acc00 = {0.f, 0.f, 0.f, 0.f};   // rows 0-15  x cols 0-15  (partial K)
    f32x4 acc01 = {0.f, 0.f, 0.f, 0.f};   // rows 0-15  x cols 16-31
    f32x4 acc11 = {0.f, 0.f, 0.f, 0.f};   // rows 16-31 x cols 16-31
    // (tile 10 is the i>j mirror of 01 -> never needed)

    #pragma unroll
    for (int kc = 0; kc < 128; kc += 32) {
        float4 a0 = *(const float4*)(base0 + kc);
        float4 a1 = *(const float4*)(base0 + kc + 4);
        float4 b0 = *(const float4*)(base1 + kc);
        float4 b1 = *(const float4*)(base1 + kc + 4);

        bf16x8 f0, f1;
        f0[0] = f2bf(a0.x); f0[1] = f2bf(a0.y); f0[2] = f2bf(a0.z); f0[3] = f2bf(a0.w);
        f0[4] = f2bf(a1.x); f0[5] = f2bf(a1.y); f0[6] = f2bf(a1.z); f0[7] = f2bf(a1.w);
        f1[0] = f2bf(b0.x); f1[1] = f2bf(b0.y); f1[2] = f2bf(b0.z); f1[3] = f2bf(b0.w);
        f1[4] = f2bf(b1.x); f1[5] = f2bf(b1.y); f1[6] = f2bf(b1.z); f1[7] = f2bf(b1.w);

        // A-frag and B-frag of a gram share the same per-lane data.
        acc00 = __builtin_amdgcn_mfma_f32_16x16x32_bf16(f0, f0, acc00, 0, 0, 0);
        acc01 = __builtin_amdgcn_mfma_f32_16x16x32_bf16(f0, f1, acc01, 0, 0, 0);
        acc11 = __builtin_amdgcn_mfma_f32_16x16x32_bf16(f1, f1, acc11, 0, 0, 0);
    }

    // ---- Cross-wave K-combine (pair: wv and wv^1) ----
    s_acc[wv][0][lane] = acc00;
    s_acc[wv][1][lane] = acc01;
    s_acc[wv][2][lane] = acc11;
    __syncthreads();
    {
        const int pw = wv ^ 1;
        acc00 += s_acc[pw][0][lane];
        acc01 += s_acc[pw][1][lane];
        acc11 += s_acc[pw][2][lane];
    }

    // C/D layout (m89-verified): col = lane&15, row = (lane>>4)*4 + reg.
    // Diagonal of tiles 00/11: row==col -> reg = c - 4*q when in [0,4).
    const int dreg = c - 4 * q;
    if (kh == 0 && dreg >= 0 && dreg < 4) {
        s_diag[g][c]      = acc00[dreg];   // ||u_c||^2
        s_diag[g][16 + c] = acc11[dreg];   // ||u_{16+c}||^2
    }
    __syncthreads();

    if (t < 64) {
        float d = s_diag[t >> 5][t & 31];
        s_inv[t >> 5][t & 31] = 1.0f / fmaxf(sqrtf(d), EPS_NORM);
    }
    __syncthreads();

    // ---- Loss epilogue: kh==0 wave of each pair only (wave-uniform) ----
    if (kh == 0) {
        const float invj0 = s_inv[g][c];
        const float invj1 = s_inv[g][16 + c];
        const int   sj0   = s_sch[g][c];
        const int   sj1   = s_sch[g][16 + c];

        float sum = 0.0f;
        #pragma unroll
        for (int r = 0; r < 4; ++r) {
            const int   i0    = q * 4 + r;
            const float inv_i = s_inv[g][i0];
            const int   si    = s_sch[g][i0];

            // tile 01: i = i0 (<16), j = 16+c  -> always i<j
            {
                float sim = acc01[r] * inv_i * invj1;
                sum += (si == sj1) ? (1.0f - sim) : fmaxf(sim - MARGIN, 0.0f);
            }
            if (i0 < c) {
                // tile 00: i = i0, j = c
                float sim = acc00[r] * inv_i * invj0;
                sum += (si == sj0) ? (1.0f - sim) : fmaxf(sim - MARGIN, 0.0f);
                // tile 11: i = 16+i0, j = 16+c
                float sim2 = acc11[r] * s_inv[g][16 + i0] * invj1;
                sum += (s_sch[g][16 + i0] == sj1) ? (1.0f - sim2)
                                                  : fmaxf(sim2 - MARGIN, 0.0f);
            }
        }

        // wave-64 reduction
        #pragma unroll
        for (int off = 32; off > 0; off >>= 1)
            sum += __shfl_down(sum, off, 64);

        if (lane == 0)
            atomicAdd(out, sum * NPAIR_INV);
    }
}

extern "C" void kernel_launch(void* const* d_in, const int* in_sizes, int n_in,
                              void* d_out, int out_size, void* d_ws, size_t ws_size,
                              hipStream_t stream) {
    const float* emb = (const float*)d_in[0];
    const int*   sch = (const int*)d_in[1];
    float*       out = (float*)d_out;

    hipMemsetAsync(out, 0, sizeof(float), stream);   // d_out is poisoned 0xAA
    rhyme_loss_kernel<<<dim3(2048), dim3(256), 0, stream>>>(emb, sch, out);
}

// Round 7
// 206.895 us; speedup vs baseline: 1.0800x; 1.0410x over previous
//
#include <hip/hip_runtime.h>
#include <hip/hip_bf16.h>
#include <stdint.h>

// RhymeLoss: mean over b in [0,4096), pairs i<j in [0,32) of
//   same(i,j) ? 1 - cos(u_i,u_j) : relu(cos(u_i,u_j) - 0.5)
//
// R7: TLP with OVERSUBSCRIPTION. Working model from R1-R6:
//   effective BW ~= resident_waves x ~1KB-in-flight / latency.
// Per-wave in-flight is compiler-capped at ~1 load when consumers are
// VALU/MFMA (proved R2/R3/R6); copy/fill kernels win on waves x pipelined
// loads. R6 hit the 1.7 TB/s wall at 53% occupancy because its grid
// exactly equaled machine capacity (8192 waves = 8192 slots, no surplus).
//
// Structure: 4-way K-split. Block = 256 threads = ONE batch; wave wv
// computes the partial gram over K in [wv*64, wv*64+64). 4096 blocks =
// 16384 waves = 2x wave slots -> dispatch keeps CUs full (queue never
// empties until the tail). Partial accumulators (exact: MFMA K-sum
// commutes) combine via 9 KB LDS; wave 0 owns norms + loss epilogue +
// one atomicAdd per batch. Per-lane K-chunk is one contiguous 32 B run
// (two adjacent float4s) -> minimal cache-line count per wave-load.

typedef short bf16x8 __attribute__((ext_vector_type(8)));   // 8 bf16 (4 VGPRs)
typedef float f32x4  __attribute__((ext_vector_type(4)));

#define MARGIN 0.5f
#define EPS_NORM 1e-8f
#define NPAIR_INV (1.0f / 2031616.0f)   // 1 / (4096 * 496)

// fp32 -> bf16 round-to-nearest-even (inputs are finite, no NaN handling)
static __device__ __forceinline__ short f2bf(float f) {
    unsigned u = __float_as_uint(f);
    u += 0x7fffu + ((u >> 16) & 1u);
    return (short)(u >> 16);
}

__global__ __launch_bounds__(256, 8) void rhyme_loss_kernel(
    const float* __restrict__ emb,   // [4096][32][256] fp32
    const int*   __restrict__ sch,   // [4096][32] int32
    float*       __restrict__ out)   // [1] fp32 (pre-zeroed)
{
    __shared__ f32x4 s_acc[3][3][64];   // 9,216 B: waves 1-3 partial accs
    __shared__ float s_diag[32];
    __shared__ float s_inv[32];
    __shared__ int   s_sch[32];

    const int t    = threadIdx.x;
    const int wv   = t >> 6;            // wave 0..3 = K-quarter
    const int lane = t & 63;
    const int b    = blockIdx.x;        // one batch per block

    const int q = lane >> 4;            // quad 0..3 -> k-offset q*8
    const int c = lane & 15;            // fragment row (= C col)

    if (t < 32)   // scheme, coalesced dwords
        s_sch[t] = sch[(size_t)b * 32 + t];

    // Lane's source rows: c and 16+c, K-quarter wv. The lane's 8 floats per
    // row-chunk are CONTIGUOUS: [wv*64 + kc + q*8, +8).
    const float* base0 = emb + (size_t)b * 8192 + (size_t)c * 256 + wv * 64 + q * 8;
    const float* base1 = base0 + 16 * 256;

    f32x4 acc00 = {0.f, 0.f, 0.f, 0.f};   // rows 0-15  x cols 0-15  (partial K)
    f32x4 acc01 = {0.f, 0.f, 0.f, 0.f};   // rows 0-15  x cols 16-31
    f32x4 acc11 = {0.f, 0.f, 0.f, 0.f};   // rows 16-31 x cols 16-31
    // (tile 10 is the i>j mirror of 01 -> never needed)

    #pragma unroll
    for (int kc = 0; kc < 64; kc += 32) {
        float4 a0 = *(const float4*)(base0 + kc);
        float4 a1 = *(const float4*)(base0 + kc + 4);
        float4 b0 = *(const float4*)(base1 + kc);
        float4 b1 = *(const float4*)(base1 + kc + 4);

        bf16x8 f0, f1;
        f0[0] = f2bf(a0.x); f0[1] = f2bf(a0.y); f0[2] = f2bf(a0.z); f0[3] = f2bf(a0.w);
        f0[4] = f2bf(a1.x); f0[5] = f2bf(a1.y); f0[6] = f2bf(a1.z); f0[7] = f2bf(a1.w);
        f1[0] = f2bf(b0.x); f1[1] = f2bf(b0.y); f1[2] = f2bf(b0.z); f1[3] = f2bf(b0.w);
        f1[4] = f2bf(b1.x); f1[5] = f2bf(b1.y); f1[6] = f2bf(b1.z); f1[7] = f2bf(b1.w);

        // A-frag and B-frag of a gram share the same per-lane data.
        acc00 = __builtin_amdgcn_mfma_f32_16x16x32_bf16(f0, f0, acc00, 0, 0, 0);
        acc01 = __builtin_amdgcn_mfma_f32_16x16x32_bf16(f0, f1, acc01, 0, 0, 0);
        acc11 = __builtin_amdgcn_mfma_f32_16x16x32_bf16(f1, f1, acc11, 0, 0, 0);
    }

    // ---- K-combine: waves 1-3 publish partials; wave 0 sums ----
    if (wv != 0) {
        s_acc[wv - 1][0][lane] = acc00;
        s_acc[wv - 1][1][lane] = acc01;
        s_acc[wv - 1][2][lane] = acc11;
    }
    __syncthreads();

    if (wv == 0) {
        #pragma unroll
        for (int p = 0; p < 3; ++p) {
            acc00 += s_acc[p][0][lane];
            acc01 += s_acc[p][1][lane];
            acc11 += s_acc[p][2][lane];
        }

        // C/D layout (m89-verified): col = lane&15, row = (lane>>4)*4 + reg.
        // Diagonal of tiles 00/11: row==col -> reg = c - 4*q when in [0,4).
        const int dreg = c - 4 * q;
        if (dreg >= 0 && dreg < 4) {
            s_diag[c]      = acc00[dreg];   // ||u_c||^2
            s_diag[16 + c] = acc11[dreg];   // ||u_{16+c}||^2
        }
        // Intra-wave producer->consumer through LDS: s_waitcnt lgkmcnt
        // ordering within the wave; lanes of THIS wave wrote all 32 diags.
        __builtin_amdgcn_wave_barrier();
        if (lane < 32)
            s_inv[lane] = 1.0f / fmaxf(sqrtf(s_diag[lane]), EPS_NORM);
        __builtin_amdgcn_wave_barrier();

        const float invj0 = s_inv[c];
        const float invj1 = s_inv[16 + c];
        const int   sj0   = s_sch[c];
        const int   sj1   = s_sch[16 + c];

        float sum = 0.0f;
        #pragma unroll
        for (int r = 0; r < 4; ++r) {
            const int   i0    = q * 4 + r;
            const float inv_i = s_inv[i0];
            const int   si    = s_sch[i0];

            // tile 01: i = i0 (<16), j = 16+c  -> always i<j
            {
                float sim = acc01[r] * inv_i * invj1;
                sum += (si == sj1) ? (1.0f - sim) : fmaxf(sim - MARGIN, 0.0f);
            }
            if (i0 < c) {
                // tile 00: i = i0, j = c
                float sim = acc00[r] * inv_i * invj0;
                sum += (si == sj0) ? (1.0f - sim) : fmaxf(sim - MARGIN, 0.0f);
                // tile 11: i = 16+i0, j = 16+c
                float sim2 = acc11[r] * s_inv[16 + i0] * invj1;
                sum += (s_sch[16 + i0] == sj1) ? (1.0f - sim2)
                                               : fmaxf(sim2 - MARGIN, 0.0f);
            }
        }

        // wave-64 reduction
        #pragma unroll
        for (int off = 32; off > 0; off >>= 1)
            sum += __shfl_down(sum, off, 64);

        if (lane == 0)
            atomicAdd(out, sum * NPAIR_INV);
    }
}

extern "C" void kernel_launch(void* const* d_in, const int* in_sizes, int n_in,
                              void* d_out, int out_size, void* d_ws, size_t ws_size,
                              hipStream_t stream) {
    const float* emb = (const float*)d_in[0];
    const int*   sch = (const int*)d_in[1];
    float*       out = (float*)d_out;

    hipMemsetAsync(out, 0, sizeof(float), stream);   // d_out is poisoned 0xAA
    rhyme_loss_kernel<<<dim3(4096), dim3(256), 0, stream>>>(emb, sch, out);
}